// Round 4
// baseline (58.333 us; speedup 1.0000x reference)
//
#include <hip/hip_runtime.h>
#include <cstdint>
#include <cstddef>

#define HID 128
#define A_DIM 32

// ws layout (floats):
//   [0, 128)         Wa1 = W @ a_w[:128]
//   [128, 256)       Wa2 = W @ a_w[128:]
//   [256, 16640)     PT[o][d] = sum_h W[d][h]*out_w[o][h]   (= (W @ out_w^T)^T)
// total ~66 KB

// ---- k0: PT (blocks 0..63) + Wa1/Wa2 (block 64) ----
__global__ __launch_bounds__(256) void prep_kernel(const float* __restrict__ W,
                                                   const float* __restrict__ a_w,
                                                   const float* __restrict__ out_w,
                                                   float* __restrict__ ws) {
    const int tid = threadIdx.x;
    const float4* W4 = reinterpret_cast<const float4*>(W);
    if (blockIdx.x < 64) {
        const int g = blockIdx.x * 256 + tid;
        const int o = g >> 7, d = g & 127;
        const float4* ow4 = reinterpret_cast<const float4*>(out_w);
        float p = 0.f;
#pragma unroll 8
        for (int j = 0; j < 32; ++j) {
            float4 wv = W4[d * 32 + j];
            float4 ov = ow4[o * 32 + j];
            p += wv.x * ov.x + wv.y * ov.y + wv.z * ov.z + wv.w * ov.w;
        }
        ws[256 + o * HID + d] = p;  // transposed: PT[o][d]
    } else {
        const int row = tid & 127, which = tid >> 7;
        const float4* av = reinterpret_cast<const float4*>(a_w) + which * 32;
        float s = 0.f;
#pragma unroll 8
        for (int j = 0; j < 32; ++j) {
            float4 wv = W4[row * 32 + j];
            float4 va = av[j];
            s += wv.x * va.x + wv.y * va.y + wv.z * va.z + wv.w * va.w;
        }
        ws[tid] = s;
    }
}

// ---- k1: fused attention + output projection. One wave per (b,i) pair for
// the attention part (wave-synchronous, no barriers); ONE block barrier, then
// the block computes out = elu(U @ PT^T + b) for its 4 rows. ----
__global__ __launch_bounds__(256, 3) void fused_kernel(
    const float* __restrict__ hmat,
    const float* __restrict__ message,
    const int* __restrict__ mask,
    const float* __restrict__ ws,
    const float* __restrict__ out_b,
    float* __restrict__ out) {
    __shared__ float red[4][A_DIM][33];  // e2 partials, padded
    __shared__ float cf[4][A_DIM];       // per-wave softmax coefficients
    __shared__ float u_lds[4][HID];      // the block's 4 U rows

    const int tid = threadIdx.x;
    const int w = tid >> 6;      // wave 0..3
    const int lane = tid & 63;
    const int half = lane >> 5;  // 0/1
    const int q = lane & 31;
    const size_t bid = (size_t)blockIdx.x * 4 + w;  // flattened (b,i)

    // ---- issue all global loads up front ----
    const float4* gm4 = reinterpret_cast<const float4*>(message) + bid * (A_DIM * HID / 4);
    float4 v[16];  // rows 2i+half, cols 4q..4q+3
#pragma unroll
    for (int i = 0; i < 16; ++i) v[i] = gm4[(2 * i + half) * 32 + q];
    const float4* ws4 = reinterpret_cast<const float4*>(ws);
    float4 w1 = ws4[q];       // Wa1
    float4 w2 = ws4[32 + q];  // Wa2
    float4 h4 = (reinterpret_cast<const float4*>(hmat) + bid * 32)[q];
    float mv = (float)mask[bid * A_DIM + q];

    // ---- e1 = dot(h, Wa1) (half0 contributes; butterfly gives all lanes) ----
    float pe1 = (half == 0) ? (h4.x * w1.x + h4.y * w1.y + h4.z * w1.z + h4.w * w1.w) : 0.f;
#pragma unroll
    for (int m = 32; m >= 1; m >>= 1) pe1 += __shfl_xor(pe1, m);

    // ---- e2 row sums via padded LDS (2-way bank alias max = free) ----
#pragma unroll
    for (int i = 0; i < 16; ++i) {
        float p2 = v[i].x * w2.x + v[i].y * w2.y + v[i].z * w2.z + v[i].w * w2.w;
        red[w][2 * i + half][q] = p2;
    }
    float e2 = 0.f;
#pragma unroll
    for (int k = 0; k < 16; ++k) e2 += red[w][q][16 * half + k];
    e2 += __shfl_xor(e2, 32);

    // ---- leaky-relu, mask, softmax over the 32 rows ----
    float e = pe1 + e2;
    e = (e >= 0.f) ? e : 0.2f * e;  // LeakyReLU(0.2)
    e *= mv;                        // E_mask (masked -> 0, not -inf)
    float mx = e;
#pragma unroll
    for (int m = 16; m >= 1; m >>= 1) mx = fmaxf(mx, __shfl_xor(mx, m));
    float ex = __expf(e - mx);
    float sum = ex;
#pragma unroll
    for (int m = 16; m >= 1; m >>= 1) sum += __shfl_xor(sum, m);
    cf[w][q] = ex / sum * mv;  // alpha * m (both halves write same value)

    // ---- weighted message sum from registers ----
    float4 acc = {0.f, 0.f, 0.f, 0.f};
#pragma unroll
    for (int i = 0; i < 16; ++i) {
        float c = cf[w][2 * i + half];
        acc.x += c * v[i].x;
        acc.y += c * v[i].y;
        acc.z += c * v[i].z;
        acc.w += c * v[i].w;
    }
    acc.x += __shfl_xor(acc.x, 32);
    acc.y += __shfl_xor(acc.y, 32);
    acc.z += __shfl_xor(acc.z, 32);
    acc.w += __shfl_xor(acc.w, 32);

    if (half == 0) {
        float4 u;
        u.x = h4.x + acc.x;
        u.y = h4.y + acc.y;
        u.z = h4.z + acc.z;
        u.w = h4.w + acc.w;
        *reinterpret_cast<float4*>(&u_lds[w][4 * q]) = u;
    }
    __syncthreads();

    // ---- epilogue: out[r][o] = elu(sum_d U[r][d]*PT[o][d] + b[o]) ----
    const int g2 = tid >> 7;  // 0/1 -> rows 2g2, 2g2+1
    const int o = tid & 127;
    const float4* PT4 = reinterpret_cast<const float4*>(ws + 256) + (size_t)o * 32;
    const float4* u0 = reinterpret_cast<const float4*>(&u_lds[2 * g2][0]);
    const float4* u1 = reinterpret_cast<const float4*>(&u_lds[2 * g2 + 1][0]);
    float a0 = 0.f, a1 = 0.f;
#pragma unroll 8
    for (int k = 0; k < 32; ++k) {
        float4 pt = PT4[k];   // per-lane row slice, L1/L2-resident
        float4 x0 = u0[k];    // LDS broadcast
        float4 x1 = u1[k];    // LDS broadcast
        a0 += x0.x * pt.x + x0.y * pt.y + x0.z * pt.z + x0.w * pt.w;
        a1 += x1.x * pt.x + x1.y * pt.y + x1.z * pt.z + x1.w * pt.w;
    }
    const float b = out_b[o];
    float x = a0 + b;
    out[((size_t)blockIdx.x * 4 + 2 * g2) * HID + o] = (x > 0.f) ? x : expm1f(x);
    x = a1 + b;
    out[((size_t)blockIdx.x * 4 + 2 * g2 + 1) * HID + o] = (x > 0.f) ? x : expm1f(x);
}

extern "C" void kernel_launch(void* const* d_in, const int* in_sizes, int n_in,
                              void* d_out, int out_size, void* d_ws, size_t ws_size,
                              hipStream_t stream) {
    const float* hmat = (const float*)d_in[0];     // (256,32,128)
    const float* message = (const float*)d_in[1];  // (256,32,32,128)
    const int* mask = (const int*)d_in[2];         // (256,32,32)
    const float* W = (const float*)d_in[3];        // (128,128)
    const float* a_w = (const float*)d_in[4];      // (256,)
    const float* out_w = (const float*)d_in[5];    // (128,128)
    const float* out_b = (const float*)d_in[6];    // (128,)
    float* out = (float*)d_out;                    // (256,32,128) f32
    float* ws = (float*)d_ws;

    prep_kernel<<<65, 256, 0, stream>>>(W, a_w, out_w, ws);
    fused_kernel<<<2048, 256, 0, stream>>>(hmat, message, mask, ws, out_b, out);
}

// Round 5
// 45.025 us; speedup vs baseline: 1.2956x; 1.2956x over previous
//
#include <hip/hip_runtime.h>
#include <cstdint>
#include <cstddef>

#define HID 128
#define A_DIM 32

// ws layout (floats):
//   [0, 128)            Wa1 = W @ a_w[:128]
//   [128, 256)          Wa2 = W @ a_w[128:]
//   [256, 16640)        P[d][o] = sum_h W[d][h]*out_w[o][h]  (= W @ out_w^T)
//   [16640, +8192*128)  U[(b,i)][:] = h + weighted_msg_sum

// ---- k0: Wa1/Wa2 (8 blocks, 8 threads per output element) ----
__global__ __launch_bounds__(256) void wa_kernel(const float* __restrict__ W,
                                                 const float* __restrict__ a_w,
                                                 float* __restrict__ ws) {
    const int tid = threadIdx.x;
    const int s = blockIdx.x * 32 + (tid >> 3);  // 0..255 (0-127: Wa1, 128-255: Wa2)
    const int p8 = tid & 7;
    const int row = s & 127, which = s >> 7;
    const float4* W4 = reinterpret_cast<const float4*>(W);
    const float4* av = reinterpret_cast<const float4*>(a_w + which * HID);
    float p = 0.f;
#pragma unroll
    for (int i = 0; i < 4; ++i) {
        float4 wv = W4[row * 32 + p8 * 4 + i];
        float4 va = av[p8 * 4 + i];
        p += wv.x * va.x + wv.y * va.y + wv.z * va.z + wv.w * va.w;
    }
    p += __shfl_down(p, 4);
    p += __shfl_down(p, 2);
    p += __shfl_down(p, 1);
    if (p8 == 0) ws[s] = p;
}

#define E2_ROW(i, vv)                                                          \
    {                                                                          \
        float p2 = vv.x * w2.x + vv.y * w2.y + vv.z * w2.z + vv.w * w2.w;      \
        red[w][2 * (i) + half][q] = p2;                                        \
    }

#define WSUM_ROW(i, vv)                                                        \
    {                                                                          \
        float c = cf[w][2 * (i) + half];                                       \
        acc.x += c * vv.x;                                                     \
        acc.y += c * vv.y;                                                     \
        acc.z += c * vv.z;                                                     \
        acc.w += c * vv.w;                                                     \
    }

#define PIN4(a, b, c, d)                                                       \
    asm volatile("" : "+v"(a.x), "+v"(a.y), "+v"(a.z), "+v"(a.w),              \
                      "+v"(b.x), "+v"(b.y), "+v"(b.z), "+v"(b.w),              \
                      "+v"(c.x), "+v"(c.y), "+v"(c.z), "+v"(c.w),              \
                      "+v"(d.x), "+v"(d.y), "+v"(d.z), "+v"(d.w))

// ---- k1: blocks 0..63 compute P (consumed only by out_kernel — safe);
// blocks 64.. are attention: ONE WAVE per (b,i) pair, zero barriers. ----
__global__ __launch_bounds__(256) void attn_kernel(
    const float* __restrict__ hmat,
    const float* __restrict__ message,
    const int* __restrict__ mask,
    const float* __restrict__ W,
    const float* __restrict__ out_w,
    float* __restrict__ ws,
    float* __restrict__ U) {
    const int tid = threadIdx.x;

    if (blockIdx.x < 64) {  // ---- P = W @ out_w^T, stored P[d][o] ----
        const int g = blockIdx.x * 256 + tid;
        const int d = g >> 7, o = g & 127;
        const float4* W4 = reinterpret_cast<const float4*>(W);
        const float4* ow4 = reinterpret_cast<const float4*>(out_w);
        float p = 0.f;
#pragma unroll 8
        for (int j = 0; j < 32; ++j) {
            float4 wv = W4[d * 32 + j];
            float4 ov = ow4[o * 32 + j];
            p += wv.x * ov.x + wv.y * ov.y + wv.z * ov.z + wv.w * ov.w;
        }
        ws[256 + d * HID + o] = p;
        return;
    }

    __shared__ float red[4][A_DIM][33];
    __shared__ float cf[4][A_DIM];

    const int w = tid >> 6;
    const int lane = tid & 63;
    const int half = lane >> 5;
    const int q = lane & 31;
    const size_t bid = (size_t)(blockIdx.x - 64) * 4 + w;  // flattened (b,i)

    // ---- batch-issue ALL global loads ----
    const float4* gm4 = reinterpret_cast<const float4*>(message) + bid * (A_DIM * HID / 4);
    float4 v0 = gm4[(0 + half) * 32 + q];
    float4 v1 = gm4[(2 + half) * 32 + q];
    float4 v2 = gm4[(4 + half) * 32 + q];
    float4 v3 = gm4[(6 + half) * 32 + q];
    float4 v4 = gm4[(8 + half) * 32 + q];
    float4 v5 = gm4[(10 + half) * 32 + q];
    float4 v6 = gm4[(12 + half) * 32 + q];
    float4 v7 = gm4[(14 + half) * 32 + q];
    float4 v8 = gm4[(16 + half) * 32 + q];
    float4 v9 = gm4[(18 + half) * 32 + q];
    float4 v10 = gm4[(20 + half) * 32 + q];
    float4 v11 = gm4[(22 + half) * 32 + q];
    float4 v12 = gm4[(24 + half) * 32 + q];
    float4 v13 = gm4[(26 + half) * 32 + q];
    float4 v14 = gm4[(28 + half) * 32 + q];
    float4 v15 = gm4[(30 + half) * 32 + q];
    const float4* ws4 = reinterpret_cast<const float4*>(ws);
    float4 w1 = ws4[q];       // Wa1
    float4 w2 = ws4[32 + q];  // Wa2
    float4 h4 = (reinterpret_cast<const float4*>(hmat) + bid * 32)[q];
    float mv = (float)mask[bid * A_DIM + q];

    // Pin tile in VGPRs: forces batch completion here and keeps all 16 float4
    // live until the weighted sum (no sinking / remat / reload).
    PIN4(v0, v1, v2, v3);
    PIN4(v4, v5, v6, v7);
    PIN4(v8, v9, v10, v11);
    PIN4(v12, v13, v14, v15);

    // ---- e1 = dot(h, Wa1): half0 contributes; butterfly broadcasts ----
    float pe1 = (half == 0) ? (h4.x * w1.x + h4.y * w1.y + h4.z * w1.z + h4.w * w1.w) : 0.f;
#pragma unroll
    for (int m = 32; m >= 1; m >>= 1) pe1 += __shfl_xor(pe1, m);

    // ---- e2 partials -> padded LDS (2-way alias max = free) ----
    E2_ROW(0, v0) E2_ROW(1, v1) E2_ROW(2, v2) E2_ROW(3, v3)
    E2_ROW(4, v4) E2_ROW(5, v5) E2_ROW(6, v6) E2_ROW(7, v7)
    E2_ROW(8, v8) E2_ROW(9, v9) E2_ROW(10, v10) E2_ROW(11, v11)
    E2_ROW(12, v12) E2_ROW(13, v13) E2_ROW(14, v14) E2_ROW(15, v15)

    float e2 = 0.f;
#pragma unroll
    for (int k = 0; k < 16; ++k) e2 += red[w][q][16 * half + k];
    e2 += __shfl_xor(e2, 32);

    // ---- leaky-relu, mask, softmax over the 32 rows ----
    float e = pe1 + e2;
    e = (e >= 0.f) ? e : 0.2f * e;  // LeakyReLU(0.2)
    e *= mv;                        // E_mask (masked -> 0, not -inf)
    float mx = e;
#pragma unroll
    for (int m = 16; m >= 1; m >>= 1) mx = fmaxf(mx, __shfl_xor(mx, m));
    float ex = __expf(e - mx);
    float sum = ex;
#pragma unroll
    for (int m = 16; m >= 1; m >>= 1) sum += __shfl_xor(sum, m);
    cf[w][q] = ex / sum * mv;  // alpha * m

    // ---- weighted message sum from pinned registers ----
    float4 acc = {0.f, 0.f, 0.f, 0.f};
    WSUM_ROW(0, v0) WSUM_ROW(1, v1) WSUM_ROW(2, v2) WSUM_ROW(3, v3)
    WSUM_ROW(4, v4) WSUM_ROW(5, v5) WSUM_ROW(6, v6) WSUM_ROW(7, v7)
    WSUM_ROW(8, v8) WSUM_ROW(9, v9) WSUM_ROW(10, v10) WSUM_ROW(11, v11)
    WSUM_ROW(12, v12) WSUM_ROW(13, v13) WSUM_ROW(14, v14) WSUM_ROW(15, v15)
    acc.x += __shfl_xor(acc.x, 32);
    acc.y += __shfl_xor(acc.y, 32);
    acc.z += __shfl_xor(acc.z, 32);
    acc.w += __shfl_xor(acc.w, 32);

    if (half == 0) {
        float4 u;
        u.x = h4.x + acc.x;
        u.y = h4.y + acc.y;
        u.z = h4.z + acc.z;
        u.w = h4.w + acc.w;
        reinterpret_cast<float4*>(U)[bid * 32 + q] = u;
    }
}

// ---- k2: out = elu(U @ P + b). 16 rows/block, float4 everywhere. ----
__global__ __launch_bounds__(256) void out_kernel(
    const float* __restrict__ U,
    const float* __restrict__ ws,
    const float* __restrict__ out_b,
    float* __restrict__ out) {
    const float* P = ws + 256;
    __shared__ float u_lds[16][132];

    const int tid = threadIdx.x;
    const size_t row0 = (size_t)blockIdx.x * 16;
    const float4* gu = reinterpret_cast<const float4*>(U + row0 * HID);
#pragma unroll
    for (int i = 0; i < 2; ++i) {
        int idx = tid + i * 256;
        int r = idx >> 5, c4 = idx & 31;
        float4 vv = gu[idx];
        *reinterpret_cast<float4*>(&u_lds[r][c4 * 4]) = vv;
    }
    __syncthreads();

    const int tx = tid & 31;
    const int ty = tid >> 5;
    const float4* P4 = reinterpret_cast<const float4*>(P);

    float4 a0 = {0.f, 0.f, 0.f, 0.f}, a1 = {0.f, 0.f, 0.f, 0.f};
    for (int kg = 0; kg < 32; ++kg) {
        float4 p0 = P4[(4 * kg + 0) * 32 + tx];
        float4 p1 = P4[(4 * kg + 1) * 32 + tx];
        float4 p2 = P4[(4 * kg + 2) * 32 + tx];
        float4 p3 = P4[(4 * kg + 3) * 32 + tx];
        float4 u0 = *reinterpret_cast<const float4*>(&u_lds[2 * ty][4 * kg]);
        float4 u1 = *reinterpret_cast<const float4*>(&u_lds[2 * ty + 1][4 * kg]);
        a0.x += u0.x * p0.x + u0.y * p1.x + u0.z * p2.x + u0.w * p3.x;
        a0.y += u0.x * p0.y + u0.y * p1.y + u0.z * p2.y + u0.w * p3.y;
        a0.z += u0.x * p0.z + u0.y * p1.z + u0.z * p2.z + u0.w * p3.z;
        a0.w += u0.x * p0.w + u0.y * p1.w + u0.z * p2.w + u0.w * p3.w;
        a1.x += u1.x * p0.x + u1.y * p1.x + u1.z * p2.x + u1.w * p3.x;
        a1.y += u1.x * p0.y + u1.y * p1.y + u1.z * p2.y + u1.w * p3.y;
        a1.z += u1.x * p0.z + u1.y * p1.z + u1.z * p2.z + u1.w * p3.z;
        a1.w += u1.x * p0.w + u1.y * p1.w + u1.z * p2.w + u1.w * p3.w;
    }
    float4 b4 = reinterpret_cast<const float4*>(out_b)[tx];
    float4 o0, o1;
    float x;
    x = a0.x + b4.x; o0.x = (x > 0.f) ? x : expm1f(x);
    x = a0.y + b4.y; o0.y = (x > 0.f) ? x : expm1f(x);
    x = a0.z + b4.z; o0.z = (x > 0.f) ? x : expm1f(x);
    x = a0.w + b4.w; o0.w = (x > 0.f) ? x : expm1f(x);
    x = a1.x + b4.x; o1.x = (x > 0.f) ? x : expm1f(x);
    x = a1.y + b4.y; o1.y = (x > 0.f) ? x : expm1f(x);
    x = a1.z + b4.z; o1.z = (x > 0.f) ? x : expm1f(x);
    x = a1.w + b4.w; o1.w = (x > 0.f) ? x : expm1f(x);
    float4* out4 = reinterpret_cast<float4*>(out);
    out4[(row0 + 2 * ty) * 32 + tx] = o0;
    out4[(row0 + 2 * ty + 1) * 32 + tx] = o1;
}

extern "C" void kernel_launch(void* const* d_in, const int* in_sizes, int n_in,
                              void* d_out, int out_size, void* d_ws, size_t ws_size,
                              hipStream_t stream) {
    const float* hmat = (const float*)d_in[0];     // (256,32,128)
    const float* message = (const float*)d_in[1];  // (256,32,32,128)
    const int* mask = (const int*)d_in[2];         // (256,32,32)
    const float* W = (const float*)d_in[3];        // (128,128)
    const float* a_w = (const float*)d_in[4];      // (256,)
    const float* out_w = (const float*)d_in[5];    // (128,128)
    const float* out_b = (const float*)d_in[6];    // (128,)
    float* out = (float*)d_out;                    // (256,32,128) f32
    float* ws = (float*)d_ws;
    float* U = ws + 256 + HID * HID;

    wa_kernel<<<8, 256, 0, stream>>>(W, a_w, ws);
    attn_kernel<<<64 + 2048, 256, 0, stream>>>(hmat, message, mask, W, out_w, ws, U);
    out_kernel<<<512, 256, 0, stream>>>(U, ws, out_b, out);
}

// Round 6
// 39.016 us; speedup vs baseline: 1.4951x; 1.1540x over previous
//
#include <hip/hip_runtime.h>
#include <cstdint>
#include <cstddef>

#define HID 128
#define A_DIM 32

// ws layout (floats):
//   [0, 128)         Wa1 = W @ a_w[:128]
//   [128, 256)       Wa2 = W @ a_w[128:]
//   [256, 16640)     P[d][o] = sum_h W[d][h]*out_w[o][h]   (= W @ out_w^T)
// total ~66 KB. No U buffer: U lives in LDS inside fused_kernel.

// ---- k0: P (blocks 0..63) + Wa1/Wa2 (block 64) ----
__global__ __launch_bounds__(256) void prep_kernel(const float* __restrict__ W,
                                                   const float* __restrict__ a_w,
                                                   const float* __restrict__ out_w,
                                                   float* __restrict__ ws) {
    const int tid = threadIdx.x;
    const float4* W4 = reinterpret_cast<const float4*>(W);
    if (blockIdx.x < 64) {
        const int g = blockIdx.x * 256 + tid;
        const int d = g >> 7, o = g & 127;
        const float4* ow4 = reinterpret_cast<const float4*>(out_w);
        float p = 0.f;
#pragma unroll 8
        for (int j = 0; j < 32; ++j) {
            float4 wv = W4[d * 32 + j];   // broadcast within wave
            float4 ov = ow4[o * 32 + j];  // L2-resident
            p += wv.x * ov.x + wv.y * ov.y + wv.z * ov.z + wv.w * ov.w;
        }
        ws[256 + d * HID + o] = p;  // P[d][o], coalesced in o
    } else {
        const int row = tid & 127, which = tid >> 7;
        const float4* av = reinterpret_cast<const float4*>(a_w) + which * 32;
        float s = 0.f;
#pragma unroll 8
        for (int j = 0; j < 32; ++j) {
            float4 wv = W4[row * 32 + j];
            float4 va = av[j];
            s += wv.x * va.x + wv.y * va.y + wv.z * va.z + wv.w * va.w;
        }
        ws[tid] = s;
    }
}

#define E2_ROW(i, vv)                                                          \
    {                                                                          \
        float p2 = vv.x * w2.x + vv.y * w2.y + vv.z * w2.z + vv.w * w2.w;      \
        red[w][2 * (i) + half][q] = p2;                                        \
    }

#define WSUM_ROW(i, vv)                                                        \
    {                                                                          \
        float c = cf[w][2 * (i) + half];                                       \
        acc.x += c * vv.x;                                                     \
        acc.y += c * vv.y;                                                     \
        acc.z += c * vv.z;                                                     \
        acc.w += c * vv.w;                                                     \
    }

#define PIN4(a, b, c, d)                                                       \
    asm volatile("" : "+v"(a.x), "+v"(a.y), "+v"(a.z), "+v"(a.w),              \
                      "+v"(b.x), "+v"(b.y), "+v"(b.z), "+v"(b.w),              \
                      "+v"(c.x), "+v"(c.y), "+v"(c.z), "+v"(c.w),              \
                      "+v"(d.x), "+v"(d.y), "+v"(d.z), "+v"(d.w))

// ---- k1: fused attention (one wave per (b,i) pair, wave-synchronous) +
// in-block coalesced-P output projection. ----
__global__ __launch_bounds__(256, 4) void fused_kernel(
    const float* __restrict__ hmat,
    const float* __restrict__ message,
    const int* __restrict__ mask,
    const float* __restrict__ ws,
    const float* __restrict__ out_b,
    float* __restrict__ out) {
    __shared__ float red[4][A_DIM][33];  // e2 partials; REUSED as epilogue partials
    __shared__ float cf[4][A_DIM];
    __shared__ float u_lds[4][HID];      // the block's 4 U rows

    const int tid = threadIdx.x;
    const int w = tid >> 6;
    const int lane = tid & 63;
    const int half = lane >> 5;
    const int q = lane & 31;
    const size_t bid = (size_t)blockIdx.x * 4 + w;  // flattened (b,i)

    // ---- batch-issue ALL global loads ----
    const float4* gm4 = reinterpret_cast<const float4*>(message) + bid * (A_DIM * HID / 4);
    float4 v0 = gm4[(0 + half) * 32 + q];
    float4 v1 = gm4[(2 + half) * 32 + q];
    float4 v2 = gm4[(4 + half) * 32 + q];
    float4 v3 = gm4[(6 + half) * 32 + q];
    float4 v4 = gm4[(8 + half) * 32 + q];
    float4 v5 = gm4[(10 + half) * 32 + q];
    float4 v6 = gm4[(12 + half) * 32 + q];
    float4 v7 = gm4[(14 + half) * 32 + q];
    float4 v8 = gm4[(16 + half) * 32 + q];
    float4 v9 = gm4[(18 + half) * 32 + q];
    float4 v10 = gm4[(20 + half) * 32 + q];
    float4 v11 = gm4[(22 + half) * 32 + q];
    float4 v12 = gm4[(24 + half) * 32 + q];
    float4 v13 = gm4[(26 + half) * 32 + q];
    float4 v14 = gm4[(28 + half) * 32 + q];
    float4 v15 = gm4[(30 + half) * 32 + q];
    const float4* ws4 = reinterpret_cast<const float4*>(ws);
    float4 w1 = ws4[q];       // Wa1
    float4 w2 = ws4[32 + q];  // Wa2
    float4 h4 = (reinterpret_cast<const float4*>(hmat) + bid * 32)[q];
    float mv = (float)mask[bid * A_DIM + q];

    PIN4(v0, v1, v2, v3);
    PIN4(v4, v5, v6, v7);
    PIN4(v8, v9, v10, v11);
    PIN4(v12, v13, v14, v15);

    // ---- e1 = dot(h, Wa1) ----
    float pe1 = (half == 0) ? (h4.x * w1.x + h4.y * w1.y + h4.z * w1.z + h4.w * w1.w) : 0.f;
#pragma unroll
    for (int m = 32; m >= 1; m >>= 1) pe1 += __shfl_xor(pe1, m);

    // ---- e2 partials -> padded LDS ----
    E2_ROW(0, v0) E2_ROW(1, v1) E2_ROW(2, v2) E2_ROW(3, v3)
    E2_ROW(4, v4) E2_ROW(5, v5) E2_ROW(6, v6) E2_ROW(7, v7)
    E2_ROW(8, v8) E2_ROW(9, v9) E2_ROW(10, v10) E2_ROW(11, v11)
    E2_ROW(12, v12) E2_ROW(13, v13) E2_ROW(14, v14) E2_ROW(15, v15)

    float e2 = 0.f;
#pragma unroll
    for (int k = 0; k < 16; ++k) e2 += red[w][q][16 * half + k];
    e2 += __shfl_xor(e2, 32);

    // ---- leaky-relu, mask, softmax ----
    float e = pe1 + e2;
    e = (e >= 0.f) ? e : 0.2f * e;  // LeakyReLU(0.2)
    e *= mv;                        // E_mask (masked -> 0, not -inf)
    float mx = e;
#pragma unroll
    for (int m = 16; m >= 1; m >>= 1) mx = fmaxf(mx, __shfl_xor(mx, m));
    float ex = __expf(e - mx);
    float sum = ex;
#pragma unroll
    for (int m = 16; m >= 1; m >>= 1) sum += __shfl_xor(sum, m);
    cf[w][q] = ex / sum * mv;  // alpha * m

    // ---- weighted message sum from registers ----
    float4 acc = {0.f, 0.f, 0.f, 0.f};
    WSUM_ROW(0, v0) WSUM_ROW(1, v1) WSUM_ROW(2, v2) WSUM_ROW(3, v3)
    WSUM_ROW(4, v4) WSUM_ROW(5, v5) WSUM_ROW(6, v6) WSUM_ROW(7, v7)
    WSUM_ROW(8, v8) WSUM_ROW(9, v9) WSUM_ROW(10, v10) WSUM_ROW(11, v11)
    WSUM_ROW(12, v12) WSUM_ROW(13, v13) WSUM_ROW(14, v14) WSUM_ROW(15, v15)
    acc.x += __shfl_xor(acc.x, 32);
    acc.y += __shfl_xor(acc.y, 32);
    acc.z += __shfl_xor(acc.z, 32);
    acc.w += __shfl_xor(acc.w, 32);

    if (half == 0) {
        float4 u;
        u.x = h4.x + acc.x;
        u.y = h4.y + acc.y;
        u.z = h4.z + acc.z;
        u.w = h4.w + acc.w;
        *reinterpret_cast<float4*>(&u_lds[w][4 * q]) = u;
    }
    __syncthreads();

    // ---- epilogue: out[r][o] = elu(sum_d U[r][d]*P[d][o] + b[o]) ----
    // Phase 1: 128 threads = 32 o-chunks x 4 d-quarters; all 4 rows in regs
    // (P float4 loads are coalesced and reused across rows).
    float4* part4 = reinterpret_cast<float4*>(&red[0][0][0]);  // alias (red is dead)
    const float4* P4 = reinterpret_cast<const float4*>(ws + 256);
    if (tid < 128) {
        const int tx = tid & 31;  // o-chunk
        const int dq = tid >> 5;  // d-quarter
        float4 a0 = {0.f, 0.f, 0.f, 0.f}, a1 = a0, a2 = a0, a3 = a0;
#pragma unroll 2
        for (int kg = 0; kg < 8; ++kg) {
#pragma unroll
            for (int j = 0; j < 4; ++j) {
                const int d = dq * 32 + kg * 4 + j;
                float4 p = P4[d * 32 + tx];  // coalesced, L2-resident
                float u0 = u_lds[0][d], u1 = u_lds[1][d];  // LDS broadcast
                float u2 = u_lds[2][d], u3 = u_lds[3][d];
                a0.x += u0 * p.x; a0.y += u0 * p.y; a0.z += u0 * p.z; a0.w += u0 * p.w;
                a1.x += u1 * p.x; a1.y += u1 * p.y; a1.z += u1 * p.z; a1.w += u1 * p.w;
                a2.x += u2 * p.x; a2.y += u2 * p.y; a2.z += u2 * p.z; a2.w += u2 * p.w;
                a3.x += u3 * p.x; a3.y += u3 * p.y; a3.z += u3 * p.z; a3.w += u3 * p.w;
            }
        }
        part4[(dq * 4 + 0) * 32 + tx] = a0;
        part4[(dq * 4 + 1) * 32 + tx] = a1;
        part4[(dq * 4 + 2) * 32 + tx] = a2;
        part4[(dq * 4 + 3) * 32 + tx] = a3;
    }
    __syncthreads();

    // Phase 2: 128 threads = 4 rows x 32 o-chunks; combine d-quarters + bias + elu.
    if (tid < 128) {
        const int tx = tid & 31;
        const int r = tid >> 5;
        float4 s0 = part4[(0 + r) * 32 + tx];
        float4 s1 = part4[(4 + r) * 32 + tx];
        float4 s2 = part4[(8 + r) * 32 + tx];
        float4 s3 = part4[(12 + r) * 32 + tx];
        float4 b4 = reinterpret_cast<const float4*>(out_b)[tx];
        float4 o4;
        float x;
        x = s0.x + s1.x + s2.x + s3.x + b4.x; o4.x = (x > 0.f) ? x : expm1f(x);
        x = s0.y + s1.y + s2.y + s3.y + b4.y; o4.y = (x > 0.f) ? x : expm1f(x);
        x = s0.z + s1.z + s2.z + s3.z + b4.z; o4.z = (x > 0.f) ? x : expm1f(x);
        x = s0.w + s1.w + s2.w + s3.w + b4.w; o4.w = (x > 0.f) ? x : expm1f(x);
        reinterpret_cast<float4*>(out)[((size_t)blockIdx.x * 4 + r) * 32 + tx] = o4;
    }
}

extern "C" void kernel_launch(void* const* d_in, const int* in_sizes, int n_in,
                              void* d_out, int out_size, void* d_ws, size_t ws_size,
                              hipStream_t stream) {
    const float* hmat = (const float*)d_in[0];     // (256,32,128)
    const float* message = (const float*)d_in[1];  // (256,32,32,128)
    const int* mask = (const int*)d_in[2];         // (256,32,32)
    const float* W = (const float*)d_in[3];        // (128,128)
    const float* a_w = (const float*)d_in[4];      // (256,)
    const float* out_w = (const float*)d_in[5];    // (128,128)
    const float* out_b = (const float*)d_in[6];    // (128,)
    float* out = (float*)d_out;                    // (256,32,128) f32
    float* ws = (float*)d_ws;

    prep_kernel<<<65, 256, 0, stream>>>(W, a_w, out_w, ws);
    fused_kernel<<<2048, 256, 0, stream>>>(hmat, message, mask, ws, out_b, out);
}

// Round 7
// 36.198 us; speedup vs baseline: 1.6115x; 1.0779x over previous
//
#include <hip/hip_runtime.h>
#include <cstdint>
#include <cstddef>

#define HID 128
#define A_DIM 32

// ws layout (floats):
//   [0, 128)         Wa1 = W @ a_w[:128]
//   [128, 256)       Wa2 = W @ a_w[128:]
//   [256, 16640)     P[d][o] = sum_h W[d][h]*out_w[o][h]   (= W @ out_w^T)
// total ~66 KB. U lives in LDS inside fused_kernel.

// ---- k0: P (blocks 0..63) + Wa1/Wa2 (block 64) ----
__global__ __launch_bounds__(256) void prep_kernel(const float* __restrict__ W,
                                                   const float* __restrict__ a_w,
                                                   const float* __restrict__ out_w,
                                                   float* __restrict__ ws) {
    const int tid = threadIdx.x;
    const float4* W4 = reinterpret_cast<const float4*>(W);
    if (blockIdx.x < 64) {
        const int g = blockIdx.x * 256 + tid;
        const int d = g >> 7, o = g & 127;
        const float4* ow4 = reinterpret_cast<const float4*>(out_w);
        float p = 0.f;
#pragma unroll 8
        for (int j = 0; j < 32; ++j) {
            float4 wv = W4[d * 32 + j];   // broadcast within wave
            float4 ov = ow4[o * 32 + j];  // L2-resident
            p += wv.x * ov.x + wv.y * ov.y + wv.z * ov.z + wv.w * ov.w;
        }
        ws[256 + d * HID + o] = p;  // P[d][o], coalesced in o
    } else {
        const int row = tid & 127, which = tid >> 7;
        const float4* av = reinterpret_cast<const float4*>(a_w) + which * 32;
        float s = 0.f;
#pragma unroll 8
        for (int j = 0; j < 32; ++j) {
            float4 wv = W4[row * 32 + j];
            float4 va = av[j];
            s += wv.x * va.x + wv.y * va.y + wv.z * va.z + wv.w * va.w;
        }
        ws[tid] = s;
    }
}

#define E2_ROW(i, vv)                                                          \
    {                                                                          \
        float p2 = vv.x * w2.x + vv.y * w2.y + vv.z * w2.z + vv.w * w2.w;      \
        red[w][2 * (i) + half][q] = p2;                                        \
    }

#define WSUM_ROW(i, vv)                                                        \
    {                                                                          \
        float c = cf[w][2 * (i) + half];                                       \
        acc.x += c * vv.x;                                                     \
        acc.y += c * vv.y;                                                     \
        acc.z += c * vv.z;                                                     \
        acc.w += c * vv.w;                                                     \
    }

#define PIN4(a, b, c, d)                                                       \
    asm volatile("" : "+v"(a.x), "+v"(a.y), "+v"(a.z), "+v"(a.w),              \
                      "+v"(b.x), "+v"(b.y), "+v"(b.z), "+v"(b.w),              \
                      "+v"(c.x), "+v"(c.y), "+v"(c.z), "+v"(c.w),              \
                      "+v"(d.x), "+v"(d.y), "+v"(d.z), "+v"(d.w))

// ---- k1: fused attention (one wave per (b,i) pair, wave-synchronous) +
// in-block coalesced-P output projection using ALL 256 threads. ----
__global__ __launch_bounds__(256, 4) void fused_kernel(
    const float* __restrict__ hmat,
    const float* __restrict__ message,
    const int* __restrict__ mask,
    const float* __restrict__ ws,
    const float* __restrict__ out_b,
    float* __restrict__ out) {
    __shared__ float red[4][A_DIM][33];  // e2 partials; REUSED as epilogue partials (16.9KB >= 16KB)
    __shared__ float cf[4][A_DIM];
    __shared__ float u_lds[4][HID];      // the block's 4 U rows

    const int tid = threadIdx.x;
    const int w = tid >> 6;
    const int lane = tid & 63;
    const int half = lane >> 5;
    const int q = lane & 31;
    const size_t bid = (size_t)blockIdx.x * 4 + w;  // flattened (b,i)

    // ---- batch-issue ALL global loads ----
    const float4* gm4 = reinterpret_cast<const float4*>(message) + bid * (A_DIM * HID / 4);
    float4 v0 = gm4[(0 + half) * 32 + q];
    float4 v1 = gm4[(2 + half) * 32 + q];
    float4 v2 = gm4[(4 + half) * 32 + q];
    float4 v3 = gm4[(6 + half) * 32 + q];
    float4 v4 = gm4[(8 + half) * 32 + q];
    float4 v5 = gm4[(10 + half) * 32 + q];
    float4 v6 = gm4[(12 + half) * 32 + q];
    float4 v7 = gm4[(14 + half) * 32 + q];
    float4 v8 = gm4[(16 + half) * 32 + q];
    float4 v9 = gm4[(18 + half) * 32 + q];
    float4 v10 = gm4[(20 + half) * 32 + q];
    float4 v11 = gm4[(22 + half) * 32 + q];
    float4 v12 = gm4[(24 + half) * 32 + q];
    float4 v13 = gm4[(26 + half) * 32 + q];
    float4 v14 = gm4[(28 + half) * 32 + q];
    float4 v15 = gm4[(30 + half) * 32 + q];
    const float4* ws4 = reinterpret_cast<const float4*>(ws);
    float4 w1 = ws4[q];       // Wa1
    float4 w2 = ws4[32 + q];  // Wa2
    float4 h4 = (reinterpret_cast<const float4*>(hmat) + bid * 32)[q];
    float mv = (float)mask[bid * A_DIM + q];

    PIN4(v0, v1, v2, v3);
    PIN4(v4, v5, v6, v7);
    PIN4(v8, v9, v10, v11);
    PIN4(v12, v13, v14, v15);

    // ---- e1 = dot(h, Wa1) ----
    float pe1 = (half == 0) ? (h4.x * w1.x + h4.y * w1.y + h4.z * w1.z + h4.w * w1.w) : 0.f;
#pragma unroll
    for (int m = 32; m >= 1; m >>= 1) pe1 += __shfl_xor(pe1, m);

    // ---- e2 partials -> padded LDS ----
    E2_ROW(0, v0) E2_ROW(1, v1) E2_ROW(2, v2) E2_ROW(3, v3)
    E2_ROW(4, v4) E2_ROW(5, v5) E2_ROW(6, v6) E2_ROW(7, v7)
    E2_ROW(8, v8) E2_ROW(9, v9) E2_ROW(10, v10) E2_ROW(11, v11)
    E2_ROW(12, v12) E2_ROW(13, v13) E2_ROW(14, v14) E2_ROW(15, v15)

    float e2 = 0.f;
#pragma unroll
    for (int k = 0; k < 16; ++k) e2 += red[w][q][16 * half + k];
    e2 += __shfl_xor(e2, 32);

    // ---- leaky-relu, mask, softmax (no max-subtract: |E| <~ 8, f32-safe) ----
    float e = pe1 + e2;
    e = (e >= 0.f) ? e : 0.2f * e;  // LeakyReLU(0.2)
    e *= mv;                        // E_mask (masked -> 0, not -inf)
    float ex = __expf(e);
    float sum = ex;
#pragma unroll
    for (int m = 16; m >= 1; m >>= 1) sum += __shfl_xor(sum, m);
    cf[w][q] = ex / sum * mv;  // alpha * m

    // ---- weighted message sum from registers ----
    float4 acc = {0.f, 0.f, 0.f, 0.f};
    WSUM_ROW(0, v0) WSUM_ROW(1, v1) WSUM_ROW(2, v2) WSUM_ROW(3, v3)
    WSUM_ROW(4, v4) WSUM_ROW(5, v5) WSUM_ROW(6, v6) WSUM_ROW(7, v7)
    WSUM_ROW(8, v8) WSUM_ROW(9, v9) WSUM_ROW(10, v10) WSUM_ROW(11, v11)
    WSUM_ROW(12, v12) WSUM_ROW(13, v13) WSUM_ROW(14, v14) WSUM_ROW(15, v15)
    acc.x += __shfl_xor(acc.x, 32);
    acc.y += __shfl_xor(acc.y, 32);
    acc.z += __shfl_xor(acc.z, 32);
    acc.w += __shfl_xor(acc.w, 32);

    if (half == 0) {
        float4 u;
        u.x = h4.x + acc.x;
        u.y = h4.y + acc.y;
        u.z = h4.z + acc.z;
        u.w = h4.w + acc.w;
        *reinterpret_cast<float4*>(&u_lds[w][4 * q]) = u;
    }

    // ---- epilogue: out[r][o] = elu(sum_d U[r][d]*P[d][o] + b[o]) ----
    // ALL 256 threads: tx = o-chunk (32), dq = d-group (8 groups of 16 d).
    const int tx = tid & 31;
    const int dq = tid >> 5;
    const float4* P4 = reinterpret_cast<const float4*>(ws + 256);
    // Prefetch this thread's 16 P rows into regs BEFORE the barrier (tile regs
    // are dead now; overlaps L2 latency with other waves' attention tails).
    float4 p[16];
#pragma unroll
    for (int j = 0; j < 16; ++j) p[j] = P4[(dq * 16 + j) * 32 + tx];
    __syncthreads();

    float4 a0 = {0.f, 0.f, 0.f, 0.f}, a1 = a0, a2 = a0, a3 = a0;
#pragma unroll
    for (int j = 0; j < 16; ++j) {
        const int d = dq * 16 + j;
        float u0 = u_lds[0][d], u1 = u_lds[1][d];  // LDS broadcast
        float u2 = u_lds[2][d], u3 = u_lds[3][d];
        a0.x += u0 * p[j].x; a0.y += u0 * p[j].y; a0.z += u0 * p[j].z; a0.w += u0 * p[j].w;
        a1.x += u1 * p[j].x; a1.y += u1 * p[j].y; a1.z += u1 * p[j].z; a1.w += u1 * p[j].w;
        a2.x += u2 * p[j].x; a2.y += u2 * p[j].y; a2.z += u2 * p[j].z; a2.w += u2 * p[j].w;
        a3.x += u3 * p[j].x; a3.y += u3 * p[j].y; a3.z += u3 * p[j].z; a3.w += u3 * p[j].w;
    }
    __syncthreads();  // red is dead for ALL waves now; reuse as partials
    float4* part4 = reinterpret_cast<float4*>(&red[0][0][0]);
    part4[(dq * 4 + 0) * 32 + tx] = a0;
    part4[(dq * 4 + 1) * 32 + tx] = a1;
    part4[(dq * 4 + 2) * 32 + tx] = a2;
    part4[(dq * 4 + 3) * 32 + tx] = a3;
    __syncthreads();

    // Combine 8 d-groups + bias + elu: 128 threads = 4 rows x 32 o-chunks.
    if (tid < 128) {
        const int r = tid >> 5;
        float4 s = part4[r * 32 + tx];
#pragma unroll
        for (int g = 1; g < 8; ++g) {
            float4 t = part4[(g * 4 + r) * 32 + tx];
            s.x += t.x; s.y += t.y; s.z += t.z; s.w += t.w;
        }
        float4 b4 = reinterpret_cast<const float4*>(out_b)[tx];
        float4 o4;
        float x;
        x = s.x + b4.x; o4.x = (x > 0.f) ? x : expm1f(x);
        x = s.y + b4.y; o4.y = (x > 0.f) ? x : expm1f(x);
        x = s.z + b4.z; o4.z = (x > 0.f) ? x : expm1f(x);
        x = s.w + b4.w; o4.w = (x > 0.f) ? x : expm1f(x);
        reinterpret_cast<float4*>(out)[((size_t)blockIdx.x * 4 + r) * 32 + tx] = o4;
    }
}

extern "C" void kernel_launch(void* const* d_in, const int* in_sizes, int n_in,
                              void* d_out, int out_size, void* d_ws, size_t ws_size,
                              hipStream_t stream) {
    const float* hmat = (const float*)d_in[0];     // (256,32,128)
    const float* message = (const float*)d_in[1];  // (256,32,32,128)
    const int* mask = (const int*)d_in[2];         // (256,32,32)
    const float* W = (const float*)d_in[3];        // (128,128)
    const float* a_w = (const float*)d_in[4];      // (256,)
    const float* out_w = (const float*)d_in[5];    // (128,128)
    const float* out_b = (const float*)d_in[6];    // (128,)
    float* out = (float*)d_out;                    // (256,32,128) f32
    float* ws = (float*)d_ws;

    prep_kernel<<<65, 256, 0, stream>>>(W, a_w, out_w, ws);
    fused_kernel<<<2048, 256, 0, stream>>>(hmat, message, mask, ws, out_b, out);
}

// Round 8
// 36.023 us; speedup vs baseline: 1.6193x; 1.0048x over previous
//
#include <hip/hip_runtime.h>
#include <cstdint>
#include <cstddef>

#define HID 128
#define A_DIM 32

// ws layout (floats):
//   [0, 128)         Wa1 = W @ a_w[:128]
//   [128, 256)       Wa2 = W @ a_w[128:]
//   [256, 16640)     P[d][o] = sum_h W[d][h]*out_w[o][h]   (= W @ out_w^T)
// total ~66 KB. U lives in LDS inside fused_kernel.

// ---- k0: P (blocks 0..63) + Wa1/Wa2 (block 64) ----
__global__ __launch_bounds__(256) void prep_kernel(const float* __restrict__ W,
                                                   const float* __restrict__ a_w,
                                                   const float* __restrict__ out_w,
                                                   float* __restrict__ ws) {
    const int tid = threadIdx.x;
    const float4* W4 = reinterpret_cast<const float4*>(W);
    if (blockIdx.x < 64) {
        const int g = blockIdx.x * 256 + tid;
        const int d = g >> 7, o = g & 127;
        const float4* ow4 = reinterpret_cast<const float4*>(out_w);
        float p = 0.f;
#pragma unroll 8
        for (int j = 0; j < 32; ++j) {
            float4 wv = W4[d * 32 + j];   // broadcast within wave
            float4 ov = ow4[o * 32 + j];  // L2-resident
            p += wv.x * ov.x + wv.y * ov.y + wv.z * ov.z + wv.w * ov.w;
        }
        ws[256 + d * HID + o] = p;  // P[d][o], coalesced in o
    } else {
        const int row = tid & 127, which = tid >> 7;
        const float4* av = reinterpret_cast<const float4*>(a_w) + which * 32;
        float s = 0.f;
#pragma unroll 8
        for (int j = 0; j < 32; ++j) {
            float4 wv = W4[row * 32 + j];
            float4 va = av[j];
            s += wv.x * va.x + wv.y * va.y + wv.z * va.z + wv.w * va.w;
        }
        ws[tid] = s;
    }
}

#define E2_ROW(i, vv)                                                          \
    {                                                                          \
        float p2 = vv.x * w2.x + vv.y * w2.y + vv.z * w2.z + vv.w * w2.w;      \
        red[w][2 * (i) + half][q] = p2;                                        \
    }

#define WSUM_ROW(i, vv)                                                        \
    {                                                                          \
        float c = cf[w][2 * (i) + half];                                       \
        acc.x += c * vv.x;                                                     \
        acc.y += c * vv.y;                                                     \
        acc.z += c * vv.z;                                                     \
        acc.w += c * vv.w;                                                     \
    }

#define PIN4(a, b, c, d)                                                       \
    asm volatile("" : "+v"(a.x), "+v"(a.y), "+v"(a.z), "+v"(a.w),              \
                      "+v"(b.x), "+v"(b.y), "+v"(b.z), "+v"(b.w),              \
                      "+v"(c.x), "+v"(c.y), "+v"(c.z), "+v"(c.w),              \
                      "+v"(d.x), "+v"(d.y), "+v"(d.z), "+v"(d.w))

// ---- k1: fused attention (one wave per (b,i) pair, wave-synchronous) +
// in-block coalesced-P output projection using ALL 256 threads. ----
__global__ __launch_bounds__(256, 4) void fused_kernel(
    const float* __restrict__ hmat,
    const float* __restrict__ message,
    const int* __restrict__ mask,
    const float* __restrict__ ws,
    const float* __restrict__ out_b,
    float* __restrict__ out) {
    __shared__ float red[4][A_DIM][33];  // e2 partials; REUSED as epilogue partials
    __shared__ float cf[4][A_DIM];
    __shared__ float u_lds[4][HID];      // the block's 4 U rows

    const int tid = threadIdx.x;
    const int w = tid >> 6;
    const int lane = tid & 63;
    const int half = lane >> 5;
    const int q = lane & 31;
    const size_t bid = (size_t)blockIdx.x * 4 + w;  // flattened (b,i)

    // ---- batch-issue ALL global loads ----
    const float4* gm4 = reinterpret_cast<const float4*>(message) + bid * (A_DIM * HID / 4);
    float4 v0 = gm4[(0 + half) * 32 + q];
    float4 v1 = gm4[(2 + half) * 32 + q];
    float4 v2 = gm4[(4 + half) * 32 + q];
    float4 v3 = gm4[(6 + half) * 32 + q];
    float4 v4 = gm4[(8 + half) * 32 + q];
    float4 v5 = gm4[(10 + half) * 32 + q];
    float4 v6 = gm4[(12 + half) * 32 + q];
    float4 v7 = gm4[(14 + half) * 32 + q];
    float4 v8 = gm4[(16 + half) * 32 + q];
    float4 v9 = gm4[(18 + half) * 32 + q];
    float4 v10 = gm4[(20 + half) * 32 + q];
    float4 v11 = gm4[(22 + half) * 32 + q];
    float4 v12 = gm4[(24 + half) * 32 + q];
    float4 v13 = gm4[(26 + half) * 32 + q];
    float4 v14 = gm4[(28 + half) * 32 + q];
    float4 v15 = gm4[(30 + half) * 32 + q];
    const float4* ws4 = reinterpret_cast<const float4*>(ws);
    float4 w1 = ws4[q];       // Wa1
    float4 w2 = ws4[32 + q];  // Wa2
    float4 h4 = (reinterpret_cast<const float4*>(hmat) + bid * 32)[q];
    float mv = (float)mask[bid * A_DIM + q];

    PIN4(v0, v1, v2, v3);
    PIN4(v4, v5, v6, v7);
    PIN4(v8, v9, v10, v11);
    PIN4(v12, v13, v14, v15);

    // ---- e1 = dot(h, Wa1) ----
    float pe1 = (half == 0) ? (h4.x * w1.x + h4.y * w1.y + h4.z * w1.z + h4.w * w1.w) : 0.f;
#pragma unroll
    for (int m = 32; m >= 1; m >>= 1) pe1 += __shfl_xor(pe1, m);

    // ---- e2 partials -> padded LDS ----
    E2_ROW(0, v0) E2_ROW(1, v1) E2_ROW(2, v2) E2_ROW(3, v3)
    E2_ROW(4, v4) E2_ROW(5, v5) E2_ROW(6, v6) E2_ROW(7, v7)
    E2_ROW(8, v8) E2_ROW(9, v9) E2_ROW(10, v10) E2_ROW(11, v11)
    E2_ROW(12, v12) E2_ROW(13, v13) E2_ROW(14, v14) E2_ROW(15, v15)

    float e2 = 0.f;
#pragma unroll
    for (int k = 0; k < 16; ++k) e2 += red[w][q][16 * half + k];
    e2 += __shfl_xor(e2, 32);

    // ---- leaky-relu, mask, softmax (no max-subtract: |E| <~ 8, f32-safe) ----
    float e = pe1 + e2;
    e = (e >= 0.f) ? e : 0.2f * e;  // LeakyReLU(0.2)
    e *= mv;                        // E_mask (masked -> 0, not -inf)
    float ex = __expf(e);
    float sum = ex;
#pragma unroll
    for (int m = 16; m >= 1; m >>= 1) sum += __shfl_xor(sum, m);
    cf[w][q] = ex / sum * mv;  // alpha * m

    // ---- weighted message sum from registers ----
    float4 acc = {0.f, 0.f, 0.f, 0.f};
    WSUM_ROW(0, v0) WSUM_ROW(1, v1) WSUM_ROW(2, v2) WSUM_ROW(3, v3)
    WSUM_ROW(4, v4) WSUM_ROW(5, v5) WSUM_ROW(6, v6) WSUM_ROW(7, v7)
    WSUM_ROW(8, v8) WSUM_ROW(9, v9) WSUM_ROW(10, v10) WSUM_ROW(11, v11)
    WSUM_ROW(12, v12) WSUM_ROW(13, v13) WSUM_ROW(14, v14) WSUM_ROW(15, v15)
    acc.x += __shfl_xor(acc.x, 32);
    acc.y += __shfl_xor(acc.y, 32);
    acc.z += __shfl_xor(acc.z, 32);
    acc.w += __shfl_xor(acc.w, 32);

    if (half == 0) {
        float4 u;
        u.x = h4.x + acc.x;
        u.y = h4.y + acc.y;
        u.z = h4.z + acc.z;
        u.w = h4.w + acc.w;
        *reinterpret_cast<float4*>(&u_lds[w][4 * q]) = u;
    }
    __syncthreads();  // u_lds ready; red now dead for ALL waves

    // ---- epilogue: out[r][o] = elu(sum_d U[r][d]*P[d][o] + b[o]) ----
    // ALL 256 threads: tx = o-chunk (32), dq = d-group (8 groups of 16 d).
    // P loaded inside the loop (L2-hot; 4 indep acc chains hide latency) —
    // keeps peak VGPR low so occupancy rises to 5 waves/SIMD.
    const int tx = tid & 31;
    const int dq = tid >> 5;
    const float4* P4 = reinterpret_cast<const float4*>(ws + 256);
    float4 a0 = {0.f, 0.f, 0.f, 0.f}, a1 = a0, a2 = a0, a3 = a0;
#pragma unroll
    for (int j = 0; j < 16; ++j) {
        const int d = dq * 16 + j;
        float4 p = P4[d * 32 + tx];                // coalesced, L2-resident
        float u0 = u_lds[0][d], u1 = u_lds[1][d];  // LDS broadcast
        float u2 = u_lds[2][d], u3 = u_lds[3][d];
        a0.x += u0 * p.x; a0.y += u0 * p.y; a0.z += u0 * p.z; a0.w += u0 * p.w;
        a1.x += u1 * p.x; a1.y += u1 * p.y; a1.z += u1 * p.z; a1.w += u1 * p.w;
        a2.x += u2 * p.x; a2.y += u2 * p.y; a2.z += u2 * p.z; a2.w += u2 * p.w;
        a3.x += u3 * p.x; a3.y += u3 * p.y; a3.z += u3 * p.z; a3.w += u3 * p.w;
    }
    // red is dead (all reads happened before the barrier above) — write partials now.
    float4* part4 = reinterpret_cast<float4*>(&red[0][0][0]);
    part4[(dq * 4 + 0) * 32 + tx] = a0;
    part4[(dq * 4 + 1) * 32 + tx] = a1;
    part4[(dq * 4 + 2) * 32 + tx] = a2;
    part4[(dq * 4 + 3) * 32 + tx] = a3;
    __syncthreads();

    // Combine 8 d-groups + bias + elu: 128 threads = 4 rows x 32 o-chunks.
    if (tid < 128) {
        const int r = tid >> 5;
        float4 s = part4[r * 32 + tx];
#pragma unroll
        for (int g = 1; g < 8; ++g) {
            float4 t = part4[(g * 4 + r) * 32 + tx];
            s.x += t.x; s.y += t.y; s.z += t.z; s.w += t.w;
        }
        float4 b4 = reinterpret_cast<const float4*>(out_b)[tx];
        float4 o4;
        float x;
        x = s.x + b4.x; o4.x = (x > 0.f) ? x : (__expf(x) - 1.0f);
        x = s.y + b4.y; o4.y = (x > 0.f) ? x : (__expf(x) - 1.0f);
        x = s.z + b4.z; o4.z = (x > 0.f) ? x : (__expf(x) - 1.0f);
        x = s.w + b4.w; o4.w = (x > 0.f) ? x : (__expf(x) - 1.0f);
        reinterpret_cast<float4*>(out)[((size_t)blockIdx.x * 4 + r) * 32 + tx] = o4;
    }
}

extern "C" void kernel_launch(void* const* d_in, const int* in_sizes, int n_in,
                              void* d_out, int out_size, void* d_ws, size_t ws_size,
                              hipStream_t stream) {
    const float* hmat = (const float*)d_in[0];     // (256,32,128)
    const float* message = (const float*)d_in[1];  // (256,32,32,128)
    const int* mask = (const int*)d_in[2];         // (256,32,32)
    const float* W = (const float*)d_in[3];        // (128,128)
    const float* a_w = (const float*)d_in[4];      // (256,)
    const float* out_w = (const float*)d_in[5];    // (128,128)
    const float* out_b = (const float*)d_in[6];    // (128,)
    float* out = (float*)d_out;                    // (256,32,128) f32
    float* ws = (float*)d_ws;

    prep_kernel<<<65, 256, 0, stream>>>(W, a_w, out_w, ws);
    fused_kernel<<<2048, 256, 0, stream>>>(hmat, message, mask, ws, out_b, out);
}